// Round 4
// baseline (212.543 us; speedup 1.0000x reference)
//
#include <hip/hip_runtime.h>
#include <stdint.h>

typedef _Float16 f16;
typedef _Float16 f16x4 __attribute__((ext_vector_type(4)));
typedef _Float16 f16x8 __attribute__((ext_vector_type(8)));
typedef float f32x4 __attribute__((ext_vector_type(4)));

#define G_SEQ   2048
#define DMODEL  256
#define NHEADS  8
#define DHEAD   32
#define BATCH   4
#define MWORDS  64      // mask words per row (2048/32)

#if __has_builtin(__builtin_amdgcn_exp2f)
#define EXP2(x) __builtin_amdgcn_exp2f(x)
#else
#define EXP2(x) exp2f(x)
#endif

// Q pre-scale: 1/sqrt(32) * log2(e)  -> scores land in log2 domain
#define QSCALE ((float)(0.17677669529663689 * 1.4426950408889634))

// ---------------------------------------------------------------------------
// Mask packer with runtime dtype detection (bool-as-u8 vs int32 vs float32).
// ---------------------------------------------------------------------------
__global__ __launch_bounds__(256) void pack_mask_kernel(const uint32_t* __restrict__ mraw,
                                                        uint32_t* __restrict__ bits) {
  __shared__ int s_flags;
  int t = threadIdx.x;
  if (t == 0) s_flags = 0;
  __syncthreads();
  int local = 0;
  for (int i = t; i < 1024; i += 256) {
    uint32_t x = mraw[i];
    if (x == 0x3F800000u) local |= 1;
    else if ((x & 0xFFFFFF00u) != 0u) local |= 2;
  }
  if (local) atomicOr(&s_flags, local);
  __syncthreads();
  int fl = s_flags;
  int mode = (fl & 1) ? 0 : ((fl & 2) ? 1 : 2);  // 0=f32, 1=u8, 2=i32
  int word = blockIdx.x * 256 + t;               // 131072 words total
  uint32_t out = 0;
  if (mode == 1) {
    const uint32_t* p = mraw + (size_t)word * 8;
    #pragma unroll
    for (int j = 0; j < 8; ++j) {
      uint32_t v = p[j];
      if (v & 0x000000FFu) out |= 1u << (j * 4 + 0);
      if (v & 0x0000FF00u) out |= 1u << (j * 4 + 1);
      if (v & 0x00FF0000u) out |= 1u << (j * 4 + 2);
      if (v & 0xFF000000u) out |= 1u << (j * 4 + 3);
    }
  } else {
    const uint32_t* p = mraw + (size_t)word * 32;
    #pragma unroll
    for (int j = 0; j < 32; ++j) if (p[j] != 0u) out |= 1u << j;
  }
  bits[word] = out;
}

// ---------------------------------------------------------------------------
// Weight transpose + f32->f16: in [K][N] -> out [N][K] f16.
// ---------------------------------------------------------------------------
__global__ __launch_bounds__(256) void wtrans_kernel(const float* __restrict__ in,
                                                     f16* __restrict__ out, int K, int N) {
  __shared__ float tile[32][33];
  int n0 = blockIdx.x * 32;
  int k0 = blockIdx.y * 32;
  int t  = threadIdx.x;
  int r  = t >> 3;
  int c4 = (t & 7) * 4;
  const float4 v = *(const float4*)(in + (size_t)(k0 + r) * N + n0 + c4);
  tile[r][c4 + 0] = v.x; tile[r][c4 + 1] = v.y;
  tile[r][c4 + 2] = v.z; tile[r][c4 + 3] = v.w;
  __syncthreads();
  #pragma unroll
  for (int i = 0; i < 4; ++i)
    out[(size_t)(n0 + r) * K + k0 + c4 + i] = (f16)tile[c4 + i][r];
}

// ---------------------------------------------------------------------------
// x f32 -> f16 (8192x256)
// ---------------------------------------------------------------------------
__global__ __launch_bounds__(256) void xcvt_kernel(const float* __restrict__ x,
                                                   f16* __restrict__ xh) {
  int i = (blockIdx.x * 256 + threadIdx.x) * 8;
  float4 a = *(const float4*)(x + i);
  float4 b = *(const float4*)(x + i + 4);
  f16x8 h;
  h[0] = (f16)a.x; h[1] = (f16)a.y; h[2] = (f16)a.z; h[3] = (f16)a.w;
  h[4] = (f16)b.x; h[5] = (f16)b.y; h[6] = (f16)b.z; h[7] = (f16)b.w;
  *(f16x8*)(xh + i) = h;
}

// ---------------------------------------------------------------------------
// V (B,H,G,32) f16 -> V^T (B,H,32,G) f16.  Grid (G/32, BH), 256 thr.
// ---------------------------------------------------------------------------
__global__ __launch_bounds__(256) void vtrans_kernel(const f16* __restrict__ in,
                                                     f16* __restrict__ out) {
  __shared__ f16 tile[32][36];
  int bh = blockIdx.y;
  int g0 = blockIdx.x * 32;
  int t  = threadIdx.x;
  int r  = t >> 3;          // 0..31
  int c4 = (t & 7) * 4;     // 0..28
  *(f16x4*)&tile[r][c4] = *(const f16x4*)(in + (size_t)bh * 65536 + (size_t)(g0 + r) * 32 + c4);
  __syncthreads();
  f16x4 o;
  #pragma unroll
  for (int i = 0; i < 4; ++i) o[i] = tile[c4 + i][r];
  *(f16x4*)(out + (size_t)bh * 65536 + (size_t)r * G_SEQ + g0 + c4) = o;
}

// ---------------------------------------------------------------------------
// fp16 MFMA GEMM: C[M][N] = A[M][256] * Bt[N][256]^T + bias.  A is f16.
// EPI 0: split into Q(log2-scaled)/K/V f16 (B,H,G,32).  EPI 1: f32 out.
// ---------------------------------------------------------------------------
template<int EPI>
__global__ __launch_bounds__(256) void gemm_kernel(const f16* __restrict__ Aptr,
                                                   const f16* __restrict__ Bt,
                                                   const float* __restrict__ bias,
                                                   float* __restrict__ outF,
                                                   f16* __restrict__ q_out,
                                                   f16* __restrict__ k_out,
                                                   f16* __restrict__ v_out) {
  __shared__ f16 Asl[64][40];
  __shared__ f16 Bsl[64][40];
  int t = threadIdx.x;
  int lane = t & 63;
  int wv = t >> 6;
  int wm = wv >> 1, wn = wv & 1;
  int m0 = blockIdx.x * 64;
  int n0 = blockIdx.y * 64;
  int fr = lane & 15;
  int fo = (lane >> 4) * 8;

  f32x4 acc[2][2];
  #pragma unroll
  for (int i = 0; i < 2; ++i)
    #pragma unroll
    for (int j = 0; j < 2; ++j) acc[i][j] = (f32x4){0.f, 0.f, 0.f, 0.f};

  int sr = t >> 2;
  int sc8 = (t & 3) * 8;

  for (int k0 = 0; k0 < 256; k0 += 32) {
    *(f16x8*)&Asl[sr][sc8] = *(const f16x8*)(Aptr + (size_t)(m0 + sr) * 256 + k0 + sc8);
    *(f16x8*)&Bsl[sr][sc8] = *(const f16x8*)(Bt + (size_t)(n0 + sr) * 256 + k0 + sc8);
    __syncthreads();

    f16x8 af[2], bf[2];
    #pragma unroll
    for (int mi = 0; mi < 2; ++mi) af[mi] = *(const f16x8*)&Asl[wm * 32 + mi * 16 + fr][fo];
    #pragma unroll
    for (int ni = 0; ni < 2; ++ni) bf[ni] = *(const f16x8*)&Bsl[wn * 32 + ni * 16 + fr][fo];
    #pragma unroll
    for (int mi = 0; mi < 2; ++mi)
      #pragma unroll
      for (int ni = 0; ni < 2; ++ni)
        acc[mi][ni] = __builtin_amdgcn_mfma_f32_16x16x32_f16(af[mi], bf[ni], acc[mi][ni], 0, 0, 0);
    __syncthreads();
  }

  int rg = (lane >> 4) * 4;
  #pragma unroll
  for (int mi = 0; mi < 2; ++mi) {
    #pragma unroll
    for (int ni = 0; ni < 2; ++ni) {
      int c = n0 + wn * 32 + ni * 16 + fr;
      float bv = bias[c];
      #pragma unroll
      for (int r = 0; r < 4; ++r) {
        int m = m0 + wm * 32 + mi * 16 + rg + r;
        float val = acc[mi][ni][r] + bv;
        if (EPI == 0) {
          int which = c >> 8, h = (c >> 5) & 7, d = c & 31;
          int b = m >> 11, g = m & 2047;
          size_t off = (((size_t)(b * NHEADS + h)) * G_SEQ + g) * DHEAD + d;
          f16* dst = (which == 0) ? q_out : (which == 1) ? k_out : v_out;
          dst[off] = (f16)((which == 0) ? val * QSCALE : val);
        } else {
          outF[(size_t)m * 256 + c] = val;
        }
      }
    }
  }
}

// ---------------------------------------------------------------------------
// Flash attention v2: NO K/V LDS staging, NO barriers.
// K fragments + V^T fragments read directly from global (L1/L2-resident).
// Only P round-trips through per-wave LDS. Softmax sum deferred to the end.
// Grid (32 qblocks, 32 bh), 256 thr = 4 independent waves x 16 queries.
// ---------------------------------------------------------------------------
__global__ __launch_bounds__(256) void attn_kernel(const f16* __restrict__ Q,
                                                   const f16* __restrict__ Kx,
                                                   const f16* __restrict__ VT,
                                                   const uint32_t* __restrict__ bits,
                                                   f16* __restrict__ Y) {
  __shared__ f16 Psl[4][16][72];    // per-wave P; b128 reads 2-way max

  int t = threadIdx.x;
  int lane = t & 63;
  int wv = t >> 6;
  int bh = blockIdx.y;
  int qb = blockIdx.x * 64;
  int fr = lane & 15;
  int fg = lane >> 4;

  const f16* Qb = Q  + (size_t)bh * G_SEQ * DHEAD;
  const f16* Kb = Kx + (size_t)bh * G_SEQ * DHEAD;
  const f16* Vb = VT + (size_t)bh * DHEAD * G_SEQ;   // [32][2048]

  // Q A-fragment: row=fr (query), k=8*fg+j (d)
  f16x8 qf = *(const f16x8*)(Qb + (size_t)(qb + wv * 16 + fr) * DHEAD + fg * 8);

  f32x4 o0 = (f32x4){0.f, 0.f, 0.f, 0.f};
  f32x4 o1 = (f32x4){0.f, 0.f, 0.f, 0.f};
  float mrow[4] = {-1e30f, -1e30f, -1e30f, -1e30f};
  float lrow[4] = {0.f, 0.f, 0.f, 0.f};   // per-LANE partial sums (reduced at end)
  int qrows[4];
  #pragma unroll
  for (int r = 0; r < 4; ++r) qrows[r] = qb + wv * 16 + fg * 4 + r;

  for (int kv = 0; kv < G_SEQ; kv += 64) {
    // ---- issue all global loads for this tile up front ----
    f16x8 kf[4];
    #pragma unroll
    for (int nb = 0; nb < 4; ++nb)
      kf[nb] = *(const f16x8*)(Kb + (size_t)(kv + nb * 16 + fr) * DHEAD + fg * 8);
    // V^T B-fragments: [kb chunk][o-half]: row d, contiguous keys
    f16x8 vf00 = *(const f16x8*)(Vb + (size_t)fr        * G_SEQ + kv      + fg * 8);
    f16x8 vf01 = *(const f16x8*)(Vb + (size_t)(16 + fr) * G_SEQ + kv      + fg * 8);
    f16x8 vf10 = *(const f16x8*)(Vb + (size_t)fr        * G_SEQ + kv + 32 + fg * 8);
    f16x8 vf11 = *(const f16x8*)(Vb + (size_t)(16 + fr) * G_SEQ + kv + 32 + fg * 8);
    uint32_t w0[4], w1[4];
    #pragma unroll
    for (int r = 0; r < 4; ++r) {
      w0[r] = bits[(size_t)qrows[r] * MWORDS + (kv >> 5)];
      w1[r] = bits[(size_t)qrows[r] * MWORDS + (kv >> 5) + 1];
    }

    // ---- S = Q K^T (log2 domain; Q pre-scaled by 1/sqrt(d)*log2e) ----
    f32x4 s[4];
    #pragma unroll
    for (int nb = 0; nb < 4; ++nb) {
      f32x4 z = (f32x4){0.f, 0.f, 0.f, 0.f};
      s[nb] = __builtin_amdgcn_mfma_f32_16x16x32_f16(qf, kf[nb], z, 0, 0, 0);
    }

    // ---- online softmax (max reduce per tile; sum deferred) ----
    float alpha[4];
    #pragma unroll
    for (int r = 0; r < 4; ++r) {
      float sv[4]; bool al[4];
      float mx = -1e30f;
      #pragma unroll
      for (int nb = 0; nb < 4; ++nb) {
        uint32_t wsel = (nb < 2) ? w0[r] : w1[r];
        al[nb] = (wsel >> ((nb & 1) * 16 + fr)) & 1u;
        sv[nb] = al[nb] ? s[nb][r] : -1e30f;
        mx = fmaxf(mx, sv[nb]);
      }
      #pragma unroll
      for (int off = 1; off < 16; off <<= 1) mx = fmaxf(mx, __shfl_xor(mx, off, 64));
      float mnew = fmaxf(mrow[r], mx);
      float a = EXP2(mrow[r] - mnew);
      mrow[r] = mnew;
      float ps = 0.f;
      #pragma unroll
      for (int nb = 0; nb < 4; ++nb) {
        float p = al[nb] ? EXP2(sv[nb] - mnew) : 0.f;
        ps += p;
        Psl[wv][fg * 4 + r][nb * 16 + fr] = (f16)p;
      }
      alpha[r] = a;
      lrow[r] = lrow[r] * a + ps;     // per-lane partial
    }
    #pragma unroll
    for (int r = 0; r < 4; ++r) { o0[r] *= alpha[r]; o1[r] *= alpha[r]; }

    // ---- O += P V  (P A-frags from per-wave LDS; V^T B-frags in regs) ----
    {
      f16x8 pa0 = *(const f16x8*)&Psl[wv][fr][fg * 8];
      f16x8 pa1 = *(const f16x8*)&Psl[wv][fr][32 + fg * 8];
      o0 = __builtin_amdgcn_mfma_f32_16x16x32_f16(pa0, vf00, o0, 0, 0, 0);
      o1 = __builtin_amdgcn_mfma_f32_16x16x32_f16(pa0, vf01, o1, 0, 0, 0);
      o0 = __builtin_amdgcn_mfma_f32_16x16x32_f16(pa1, vf10, o0, 0, 0, 0);
      o1 = __builtin_amdgcn_mfma_f32_16x16x32_f16(pa1, vf11, o1, 0, 0, 0);
    }
  }

  // ---- final sum reduce (once), normalize, write Y f16 (B,G,256) ----
  #pragma unroll
  for (int r = 0; r < 4; ++r) {
    #pragma unroll
    for (int off = 1; off < 16; off <<= 1) lrow[r] += __shfl_xor(lrow[r], off, 64);
  }
  int b = bh >> 3, h = bh & 7;
  #pragma unroll
  for (int r = 0; r < 4; ++r) {
    float inv = 1.0f / lrow[r];
    size_t base = ((size_t)b * G_SEQ + qrows[r]) * DMODEL + h * DHEAD;
    Y[base + fr]      = (f16)(o0[r] * inv);
    Y[base + 16 + fr] = (f16)(o1[r] * inv);
  }
}

// ---------------------------------------------------------------------------
// Workspace layout (bytes):
//   0        maskbits   524288
//   524288   WtQKV f16  393216
//   917504   WtOut f16  131072
//   1048576  Q f16      4194304   (B,H,G,32)  scaled by 1/sqrt(32)*log2e
//   5242880  K f16      4194304
//   9437184  V f16      4194304
//   13631488 Y f16      4194304   (B,G,256)
//   17825792 V^T f16    4194304   (B,H,32,G)
//   22020096 xh f16     4194304
//   total 26214400
// ---------------------------------------------------------------------------
extern "C" void kernel_launch(void* const* d_in, const int* in_sizes, int n_in,
                              void* d_out, int out_size, void* d_ws, size_t ws_size,
                              hipStream_t stream) {
  const float* x      = (const float*)d_in[0];
  const uint32_t* msk = (const uint32_t*)d_in[1];
  const float* Wqkv   = (const float*)d_in[2];
  const float* bqkv   = (const float*)d_in[3];
  const float* Wout   = (const float*)d_in[4];
  const float* bout   = (const float*)d_in[5];

  char* ws = (char*)d_ws;
  uint32_t* bits = (uint32_t*)ws;
  f16* WtQ = (f16*)(ws + 524288);
  f16* WtO = (f16*)(ws + 917504);
  f16* Qf  = (f16*)(ws + 1048576);
  f16* Kf  = (f16*)(ws + 5242880);
  f16* Vf  = (f16*)(ws + 9437184);
  f16* Yf  = (f16*)(ws + 13631488);
  f16* VfT = (f16*)(ws + 17825792);
  f16* xh  = (f16*)(ws + 22020096);

  pack_mask_kernel<<<dim3(512), dim3(256), 0, stream>>>(msk, bits);
  wtrans_kernel<<<dim3(768 / 32, 256 / 32), dim3(256), 0, stream>>>(Wqkv, WtQ, 256, 768);
  wtrans_kernel<<<dim3(256 / 32, 256 / 32), dim3(256), 0, stream>>>(Wout, WtO, 256, 256);
  xcvt_kernel<<<dim3(1024), dim3(256), 0, stream>>>(x, xh);
  gemm_kernel<0><<<dim3(128, 12), dim3(256), 0, stream>>>(xh, WtQ, bqkv, nullptr, Qf, Kf, Vf);
  vtrans_kernel<<<dim3(64, 32), dim3(256), 0, stream>>>(Vf, VfT);
  attn_kernel<<<dim3(32, 32), dim3(256), 0, stream>>>(Qf, Kf, VfT, bits, Yf);
  gemm_kernel<1><<<dim3(128, 4), dim3(256), 0, stream>>>(Yf, WtO, bout, (float*)d_out,
                                                         nullptr, nullptr, nullptr);
}

// Round 6
// 200.711 us; speedup vs baseline: 1.0590x; 1.0590x over previous
//
#include <hip/hip_runtime.h>
#include <stdint.h>

typedef _Float16 f16;
typedef _Float16 f16x4 __attribute__((ext_vector_type(4)));
typedef _Float16 f16x8 __attribute__((ext_vector_type(8)));
typedef __fp16 fp16x2_raw __attribute__((ext_vector_type(2)));
typedef float f32x4 __attribute__((ext_vector_type(4)));

#define G_SEQ   2048
#define DMODEL  256
#define NHEADS  8
#define DHEAD   32
#define MWORDS  64      // mask words per row (2048/32)

#define EXP2(x) exp2f(x)
// Q pre-scale: 1/sqrt(32) * log2(e) -> scores in log2 domain
#define QSCALE ((float)(0.17677669529663689 * 1.4426950408889634))

// ---------------------------------------------------------------------------
// prep kernel: blocks [0,512) pack mask bits; [512,704) transpose Wqkv;
// [704,768) transpose Wout.  One launch instead of three.
// ---------------------------------------------------------------------------
__global__ __launch_bounds__(256) void prep_kernel(const uint32_t* __restrict__ mraw,
                                                   uint32_t* __restrict__ bits,
                                                   const float* __restrict__ Wqkv,
                                                   f16* __restrict__ WtQ,
                                                   const float* __restrict__ Wout,
                                                   f16* __restrict__ WtO) {
  __shared__ float tile[32][33];
  __shared__ int s_flags;
  int bid = blockIdx.x;
  int t = threadIdx.x;

  if (bid < 512) {
    // ---- mask pack with runtime dtype detection ----
    if (t == 0) s_flags = 0;
    __syncthreads();
    int local = 0;
    for (int i = t; i < 1024; i += 256) {
      uint32_t x = mraw[i];
      if (x == 0x3F800000u) local |= 1;
      else if ((x & 0xFFFFFF00u) != 0u) local |= 2;
    }
    if (local) atomicOr(&s_flags, local);
    __syncthreads();
    int fl = s_flags;
    int mode = (fl & 1) ? 0 : ((fl & 2) ? 1 : 2);  // 0=f32, 1=u8, 2=i32
    int word = bid * 256 + t;                      // 131072 words total
    uint32_t out = 0;
    if (mode == 1) {
      const uint32_t* p = mraw + (size_t)word * 8;
      #pragma unroll
      for (int j = 0; j < 8; ++j) {
        uint32_t v = p[j];
        if (v & 0x000000FFu) out |= 1u << (j * 4 + 0);
        if (v & 0x0000FF00u) out |= 1u << (j * 4 + 1);
        if (v & 0x00FF0000u) out |= 1u << (j * 4 + 2);
        if (v & 0xFF000000u) out |= 1u << (j * 4 + 3);
      }
    } else {
      const uint32_t* p = mraw + (size_t)word * 32;
      #pragma unroll
      for (int j = 0; j < 32; ++j) if (p[j] != 0u) out |= 1u << j;
    }
    bits[word] = out;
  } else {
    // ---- weight transpose f32 [K][N] -> f16 [N][K] ----
    const float* in; f16* outp; int N, idx;
    if (bid < 704) { idx = bid - 512; in = Wqkv; outp = WtQ; N = 768; }
    else           { idx = bid - 704; in = Wout; outp = WtO; N = 256; }
    int nblk = N / 32;
    int n0 = (idx % nblk) * 32;
    int k0 = (idx / nblk) * 32;
    int r  = t >> 3;
    int c4 = (t & 7) * 4;
    const float4 v = *(const float4*)(in + (size_t)(k0 + r) * N + n0 + c4);
    tile[r][c4 + 0] = v.x; tile[r][c4 + 1] = v.y;
    tile[r][c4 + 2] = v.z; tile[r][c4 + 3] = v.w;
    __syncthreads();
    #pragma unroll
    for (int i = 0; i < 4; ++i)
      outp[(size_t)(n0 + r) * 256 + k0 + c4 + i] = (f16)tile[c4 + i][r];
  }
}

// ---------------------------------------------------------------------------
// fp16 MFMA GEMM: C[M][N] = A[M][256] * Bt[N][256]^T + bias.
// AF16 0: A f32 (converted at staging).  1: A f16.
// EPI 0: Q (log2-scaled) / K row-major (B,H,G,32); V written TRANSPOSED
//        (B,H,32,G) with packed b64 stores.   EPI 1: f32 out + bias.
// ---------------------------------------------------------------------------
template<int AF16, int EPI>
__global__ __launch_bounds__(256) void gemm_kernel(const void* __restrict__ Aptr,
                                                   const f16* __restrict__ Bt,
                                                   const float* __restrict__ bias,
                                                   float* __restrict__ outF,
                                                   f16* __restrict__ q_out,
                                                   f16* __restrict__ k_out,
                                                   f16* __restrict__ vt_out) {
  __shared__ f16 Asl[64][40];
  __shared__ f16 Bsl[64][40];
  int t = threadIdx.x;
  int lane = t & 63;
  int wv = t >> 6;
  int wm = wv >> 1, wn = wv & 1;
  int m0 = blockIdx.x * 64;
  int n0 = blockIdx.y * 64;
  int fr = lane & 15;
  int fo = (lane >> 4) * 8;

  f32x4 acc[2][2];
  #pragma unroll
  for (int i = 0; i < 2; ++i)
    #pragma unroll
    for (int j = 0; j < 2; ++j) acc[i][j] = (f32x4){0.f, 0.f, 0.f, 0.f};

  int sr = t >> 2;
  int sc8 = (t & 3) * 8;

  for (int k0 = 0; k0 < 256; k0 += 32) {
    if (AF16) {
      *(f16x8*)&Asl[sr][sc8] =
          *(const f16x8*)((const f16*)Aptr + (size_t)(m0 + sr) * 256 + k0 + sc8);
    } else {
      const float* ap = (const float*)Aptr + (size_t)(m0 + sr) * 256 + k0 + sc8;
      float4 v0 = *(const float4*)ap;
      float4 v1 = *(const float4*)(ap + 4);
      f16x8 h;
      h[0] = (f16)v0.x; h[1] = (f16)v0.y; h[2] = (f16)v0.z; h[3] = (f16)v0.w;
      h[4] = (f16)v1.x; h[5] = (f16)v1.y; h[6] = (f16)v1.z; h[7] = (f16)v1.w;
      *(f16x8*)&Asl[sr][sc8] = h;
    }
    *(f16x8*)&Bsl[sr][sc8] = *(const f16x8*)(Bt + (size_t)(n0 + sr) * 256 + k0 + sc8);
    __syncthreads();

    f16x8 af[2], bf[2];
    #pragma unroll
    for (int mi = 0; mi < 2; ++mi) af[mi] = *(const f16x8*)&Asl[wm * 32 + mi * 16 + fr][fo];
    #pragma unroll
    for (int ni = 0; ni < 2; ++ni) bf[ni] = *(const f16x8*)&Bsl[wn * 32 + ni * 16 + fr][fo];
    #pragma unroll
    for (int mi = 0; mi < 2; ++mi)
      #pragma unroll
      for (int ni = 0; ni < 2; ++ni)
        acc[mi][ni] = __builtin_amdgcn_mfma_f32_16x16x32_f16(af[mi], bf[ni], acc[mi][ni], 0, 0, 0);
    __syncthreads();
  }

  int rg = (lane >> 4) * 4;
  #pragma unroll
  for (int mi = 0; mi < 2; ++mi) {
    #pragma unroll
    for (int ni = 0; ni < 2; ++ni) {
      int c = n0 + wn * 32 + ni * 16 + fr;
      float bv = bias[c];
      int mbase = m0 + wm * 32 + mi * 16 + rg;
      if (EPI == 0) {
        int which = c >> 8, h = (c >> 5) & 7, d = c & 31;
        if (which == 2) {
          // V: 4 consecutive g for fixed d -> contiguous in V^T, one b64 store
          int b = mbase >> 11, g = mbase & 2047;
          f16x4 pk;
          #pragma unroll
          for (int r = 0; r < 4; ++r) pk[r] = (f16)(acc[mi][ni][r] + bv);
          *(f16x4*)(vt_out + ((size_t)(b * 8 + h) * DHEAD + d) * G_SEQ + g) = pk;
        } else {
          f16* dst = (which == 0) ? q_out : k_out;
          float sc = (which == 0) ? QSCALE : 1.0f;
          #pragma unroll
          for (int r = 0; r < 4; ++r) {
            int m = mbase + r;
            int b = m >> 11, g = m & 2047;
            dst[(((size_t)(b * 8 + h)) * G_SEQ + g) * DHEAD + d] = (f16)((acc[mi][ni][r] + bv) * sc);
          }
        }
      } else {
        #pragma unroll
        for (int r = 0; r < 4; ++r)
          outF[(size_t)(mbase + r) * 256 + c] = acc[mi][ni][r] + bv;
      }
    }
  }
}

// ---------------------------------------------------------------------------
// Flash attention v3: SWAPPED QK^T -> S^T (lane owns one query column).
//  - row-max: 15 local fmax + 2 shuffles (was 16 shuffles)
//  - mask: 1 dwordx2 load/tile/lane + nibble extract (was 8 dword loads)
//  - P: cvt_pkrtz pairs, 4 ds_write_b64/tile (was 16 b16 stores)
//  - softmax sum: per-lane deferred, reduced once after kv loop
//  - alpha/l broadcast to O-layout lanes: 4 bpermutes
// No barriers; P in wave-private LDS. Grid (32 qblocks, 32 bh), 4 waves.
// ---------------------------------------------------------------------------
__global__ __launch_bounds__(256) void attn_kernel(const f16* __restrict__ Q,
                                                   const f16* __restrict__ Kx,
                                                   const f16* __restrict__ VT,
                                                   const uint32_t* __restrict__ bits,
                                                   f16* __restrict__ Y) {
  __shared__ f16 Psl[4][16][72];

  int t = threadIdx.x;
  int lane = t & 63;
  int wv = t >> 6;
  int bh = blockIdx.y;
  int qb = blockIdx.x * 64;
  int fr = lane & 15;
  int fg = lane >> 4;

  const f16* Qb = Q  + (size_t)bh * G_SEQ * DHEAD;
  const f16* Kb = Kx + (size_t)bh * G_SEQ * DHEAD;
  const f16* Vb = VT + (size_t)bh * DHEAD * G_SEQ;   // [32][2048]

  // Q B-fragment: row=fr (query), k=8*fg+j (d)
  f16x8 qf = *(const f16x8*)(Qb + (size_t)(qb + wv * 16 + fr) * DHEAD + fg * 8);

  int qrow_own = qb + wv * 16 + fr;                  // this lane's query
  const uint2* mp = (const uint2*)(bits + (size_t)qrow_own * MWORDS);

  f32x4 o0 = (f32x4){0.f, 0.f, 0.f, 0.f};
  f32x4 o1 = (f32x4){0.f, 0.f, 0.f, 0.f};
  float m_own = -1e30f;
  float l_own = 0.f;

  for (int kv = 0; kv < G_SEQ; kv += 64) {
    // ---- global loads for this tile ----
    f16x8 kf[4];
    #pragma unroll
    for (int nb = 0; nb < 4; ++nb)
      kf[nb] = *(const f16x8*)(Kb + (size_t)(kv + nb * 16 + fr) * DHEAD + fg * 8);
    f16x8 vf00 = *(const f16x8*)(Vb + (size_t)fr        * G_SEQ + kv      + fg * 8);
    f16x8 vf01 = *(const f16x8*)(Vb + (size_t)(16 + fr) * G_SEQ + kv      + fg * 8);
    f16x8 vf10 = *(const f16x8*)(Vb + (size_t)fr        * G_SEQ + kv + 32 + fg * 8);
    f16x8 vf11 = *(const f16x8*)(Vb + (size_t)(16 + fr) * G_SEQ + kv + 32 + fg * 8);
    uint2 w = mp[kv >> 6];

    // ---- S^T = (K Q^T): lane -> col=query fr, rows=keys 4fg+r (+16nb) ----
    f32x4 s[4];
    #pragma unroll
    for (int nb = 0; nb < 4; ++nb) {
      f32x4 z = (f32x4){0.f, 0.f, 0.f, 0.f};
      s[nb] = __builtin_amdgcn_mfma_f32_16x16x32_f16(kf[nb], qf, z, 0, 0, 0);
    }

    // ---- mask: nibble per nb covering keys nb*16+4fg+{0..3} ----
    float sv[4][4];
    #pragma unroll
    for (int nb = 0; nb < 4; ++nb) {
      uint32_t wsel = (nb & 2) ? w.y : w.x;
      uint32_t nib = (wsel >> ((nb & 1) * 16 + fg * 4)) & 0xFu;
      #pragma unroll
      for (int r = 0; r < 4; ++r)
        sv[nb][r] = (nib & (1u << r)) ? s[nb][r] : -1e30f;
    }

    // ---- max: local tree (16) then 2 shuffles across fg groups ----
    float mx01 = fmaxf(fmaxf(sv[0][0], sv[0][1]), fmaxf(sv[0][2], sv[0][3]));
    float mx1  = fmaxf(fmaxf(sv[1][0], sv[1][1]), fmaxf(sv[1][2], sv[1][3]));
    float mx2  = fmaxf(fmaxf(sv[2][0], sv[2][1]), fmaxf(sv[2][2], sv[2][3]));
    float mx3  = fmaxf(fmaxf(sv[3][0], sv[3][1]), fmaxf(sv[3][2], sv[3][3]));
    float mx = fmaxf(fmaxf(mx01, mx1), fmaxf(mx2, mx3));
    mx = fmaxf(mx, __shfl_xor(mx, 16, 64));
    mx = fmaxf(mx, __shfl_xor(mx, 32, 64));

    float mnew = fmaxf(fmaxf(m_own, mx), -1e28f);
    float alpha = EXP2(m_own - mnew);
    m_own = mnew;

    // ---- P = exp2(sv - mnew)  (masked sv -> -1e30 -> exp2 -> 0) ----
    float ps = 0.f;
    #pragma unroll
    for (int nb = 0; nb < 4; ++nb) {
      float p0 = EXP2(sv[nb][0] - mnew);
      float p1 = EXP2(sv[nb][1] - mnew);
      float p2 = EXP2(sv[nb][2] - mnew);
      float p3 = EXP2(sv[nb][3] - mnew);
      ps += (p0 + p1) + (p2 + p3);
      fp16x2_raw lo = __builtin_amdgcn_cvt_pkrtz(p0, p1);
      fp16x2_raw hi = __builtin_amdgcn_cvt_pkrtz(p2, p3);
      f16x4 pk;
      pk[0] = (f16)lo[0]; pk[1] = (f16)lo[1]; pk[2] = (f16)hi[0]; pk[3] = (f16)hi[1];
      *(f16x4*)&Psl[wv][fr][nb * 16 + fg * 4] = pk;   // b64 store
    }
    l_own = l_own * alpha + ps;

    // ---- broadcast alpha to O-layout lanes (O rows = queries 4fg+r) ----
    float af0 = __shfl(alpha, fg * 4 + 0, 64);
    float af1 = __shfl(alpha, fg * 4 + 1, 64);
    float af2 = __shfl(alpha, fg * 4 + 2, 64);
    float af3 = __shfl(alpha, fg * 4 + 3, 64);
    o0[0] *= af0; o0[1] *= af1; o0[2] *= af2; o0[3] *= af3;
    o1[0] *= af0; o1[1] *= af1; o1[2] *= af2; o1[3] *= af3;

    // ---- O += P V ----
    {
      f16x8 pa0 = *(const f16x8*)&Psl[wv][fr][fg * 8];
      f16x8 pa1 = *(const f16x8*)&Psl[wv][fr][32 + fg * 8];
      o0 = __builtin_amdgcn_mfma_f32_16x16x32_f16(pa0, vf00, o0, 0, 0, 0);
      o1 = __builtin_amdgcn_mfma_f32_16x16x32_f16(pa0, vf01, o1, 0, 0, 0);
      o0 = __builtin_amdgcn_mfma_f32_16x16x32_f16(pa1, vf10, o0, 0, 0, 0);
      o1 = __builtin_amdgcn_mfma_f32_16x16x32_f16(pa1, vf11, o1, 0, 0, 0);
    }
  }

  // ---- total l per query, broadcast to O-layout lanes, write Y ----
  l_own += __shfl_xor(l_own, 16, 64);
  l_own += __shfl_xor(l_own, 32, 64);
  int b = bh >> 3, h = bh & 7;
  #pragma unroll
  for (int r = 0; r < 4; ++r) {
    float lr = __shfl(l_own, fg * 4 + r, 64);
    float inv = 1.0f / lr;
    int qrow = qb + wv * 16 + fg * 4 + r;
    size_t base = ((size_t)b * G_SEQ + qrow) * DMODEL + h * DHEAD;
    Y[base + fr]      = (f16)(o0[r] * inv);
    Y[base + 16 + fr] = (f16)(o1[r] * inv);
  }
}

// ---------------------------------------------------------------------------
// Workspace layout (bytes):
//   0        maskbits   524288
//   524288   WtQKV f16  393216
//   917504   WtOut f16  131072
//   1048576  Q f16      4194304   (B,H,G,32)  scaled by 1/sqrt(32)*log2e
//   5242880  K f16      4194304   (B,H,G,32)
//   9437184  V^T f16    4194304   (B,H,32,G)
//   13631488 Y f16      4194304   (B,G,256)
//   total 17825792
// ---------------------------------------------------------------------------
extern "C" void kernel_launch(void* const* d_in, const int* in_sizes, int n_in,
                              void* d_out, int out_size, void* d_ws, size_t ws_size,
                              hipStream_t stream) {
  const float* x      = (const float*)d_in[0];
  const uint32_t* msk = (const uint32_t*)d_in[1];
  const float* Wqkv   = (const float*)d_in[2];
  const float* bqkv   = (const float*)d_in[3];
  const float* Wout   = (const float*)d_in[4];
  const float* bout   = (const float*)d_in[5];

  char* ws = (char*)d_ws;
  uint32_t* bits = (uint32_t*)ws;
  f16* WtQ = (f16*)(ws + 524288);
  f16* WtO = (f16*)(ws + 917504);
  f16* Qf  = (f16*)(ws + 1048576);
  f16* Kf  = (f16*)(ws + 5242880);
  f16* VfT = (f16*)(ws + 9437184);
  f16* Yf  = (f16*)(ws + 13631488);

  prep_kernel<<<dim3(768), dim3(256), 0, stream>>>(msk, bits, Wqkv, WtQ, Wout, WtO);
  gemm_kernel<0, 0><<<dim3(128, 12), dim3(256), 0, stream>>>(x, WtQ, bqkv, nullptr,
                                                             Qf, Kf, VfT);
  attn_kernel<<<dim3(32, 32), dim3(256), 0, stream>>>(Qf, Kf, VfT, bits, Yf);
  gemm_kernel<1, 1><<<dim3(128, 4), dim3(256), 0, stream>>>(Yf, WtO, bout, (float*)d_out,
                                                            nullptr, nullptr, nullptr);
}